// Round 1
// baseline (731.298 us; speedup 1.0000x reference)
//
#include <hip/hip_runtime.h>

// ResnetHyper: pref/chunk MLP (fp32) + huge einsum out[c,k,w] = rep[c,:] . ws[k,w,:]
// Strategy: MLP exact in fp32 (tiny). Big GEMM (M=105,K=512,N=220000) via bf16 MFMA,
// memory-bound on streaming ws (460.8 MB fp32). rep is emitted in MFMA A-fragment
// order so the GEMM kernel needs no LDS and no __syncthreads.

typedef __bf16 bf16x8 __attribute__((ext_vector_type(8)));
typedef float f32x4 __attribute__((ext_vector_type(4)));

#define NUM_CHUNKS 105
#define HIDDEN 512
#define N_COLS 220000   // 11 * 20000
#define REP_FRAG_BYTES 114688  // 16 s * 7 t * 4 q * 16 m * 16 B

// ---------------- Kernel 1: MLP -> rep bf16 in MFMA A-fragment layout --------
// grid: 105 blocks x 256 threads
__global__ void mlp_kernel(const float* __restrict__ pref,       // [2]
                           const float* __restrict__ pref_emb,   // [2][64]
                           const float* __restrict__ chunk_emb,  // [105][64]
                           const float* __restrict__ W1, const float* __restrict__ b1,
                           const float* __restrict__ W2, const float* __restrict__ b2,
                           const float* __restrict__ W3, const float* __restrict__ b3,
                           __bf16* __restrict__ repf) {
  __shared__ float x[128];
  __shared__ float h1[512];
  __shared__ float h2[512];
  const int tid = threadIdx.x;
  const int c = blockIdx.x;

  if (tid < 64) {
    x[tid] = pref[0] * pref_emb[tid] + pref[1] * pref_emb[64 + tid];
  } else if (tid < 128) {
    x[tid] = chunk_emb[c * 64 + (tid - 64)];
  }
  __syncthreads();

  // layer 1: h1 = relu(x @ W1.T + b1), W1[j] is 128 contiguous floats
  for (int jj = tid; jj < 512; jj += 256) {
    float s = b1[jj];
    const f32x4* wr = (const f32x4*)(W1 + jj * 128);
#pragma unroll
    for (int i = 0; i < 32; ++i) {
      f32x4 w = wr[i];
      s += w[0] * x[i * 4 + 0] + w[1] * x[i * 4 + 1] +
           w[2] * x[i * 4 + 2] + w[3] * x[i * 4 + 3];
    }
    h1[jj] = fmaxf(s, 0.f);
  }
  __syncthreads();

  // layer 2
  for (int jj = tid; jj < 512; jj += 256) {
    float s = b2[jj];
    const f32x4* wr = (const f32x4*)(W2 + jj * 512);
#pragma unroll 8
    for (int i = 0; i < 128; ++i) {
      f32x4 w = wr[i];
      s += w[0] * h1[i * 4 + 0] + w[1] * h1[i * 4 + 1] +
           w[2] * h1[i * 4 + 2] + w[3] * h1[i * 4 + 3];
    }
    h2[jj] = fmaxf(s, 0.f);
  }
  __syncthreads();

  // layer 3 (no relu) + scatter into A-fragment layout:
  // for chunk m=c, k=jj:  s=k>>5, q=(k>>3)&3, j=k&7, t=m>>4, mm=m&15
  // chunk index = ((s*7 + t)*4 + q)*16 + mm ; element j inside the 8-elem chunk
  const int t = c >> 4, mmc = c & 15;
  for (int jj = tid; jj < 512; jj += 256) {
    float s = b3[jj];
    const f32x4* wr = (const f32x4*)(W3 + jj * 512);
#pragma unroll 8
    for (int i = 0; i < 128; ++i) {
      f32x4 w = wr[i];
      s += w[0] * h2[i * 4 + 0] + w[1] * h2[i * 4 + 1] +
           w[2] * h2[i * 4 + 2] + w[3] * h2[i * 4 + 3];
    }
    const int ss = jj >> 5, qq = (jj >> 3) & 3, j = jj & 7;
    const long idx = (((long)(ss * 7 + t) * 4 + qq) * 16 + mmc) * 8 + j;
    repf[idx] = (__bf16)s;
  }
}

// ---------------- Kernel 2: C[105 x 220000] = rep @ ws^T via bf16 MFMA -------
// grid: 6875 blocks x 64 threads (1 wave/block, 32 N-cols per wave)
__global__ void gemm_ws(const float* __restrict__ ws,    // [220000][512]
                        const bf16x8* __restrict__ repf, // fragment chunks
                        float* __restrict__ out) {       // [105][220000]
  const int lane = threadIdx.x;   // 0..63
  const int q = lane >> 4;
  const int mm = lane & 15;
  const long cb = (long)blockIdx.x * 32;
  const long col0 = cb + mm;
  const long col1 = col0 + 16;

  // per K-step s (32 elems): lane loads ws[col][s*32 + q*8 .. +8)
  const f32x4* w0 = (const f32x4*)(ws + col0 * 512) + q * 2;
  const f32x4* w1 = (const f32x4*)(ws + col1 * 512) + q * 2;

  f32x4 acc0[7], acc1[7];
#pragma unroll
  for (int t = 0; t < 7; ++t) {
    acc0[t] = (f32x4){0.f, 0.f, 0.f, 0.f};
    acc1[t] = (f32x4){0.f, 0.f, 0.f, 0.f};
  }

#pragma unroll 2
  for (int s = 0; s < 16; ++s) {
    f32x4 x0 = __builtin_nontemporal_load(w0 + s * 8);
    f32x4 x1 = __builtin_nontemporal_load(w0 + s * 8 + 1);
    f32x4 y0 = __builtin_nontemporal_load(w1 + s * 8);
    f32x4 y1 = __builtin_nontemporal_load(w1 + s * 8 + 1);
    bf16x8 b0, b1;
#pragma unroll
    for (int j = 0; j < 4; ++j) {
      b0[j] = (__bf16)x0[j];
      b0[4 + j] = (__bf16)x1[j];
      b1[j] = (__bf16)y0[j];
      b1[4 + j] = (__bf16)y1[j];
    }
    const bf16x8* ap = repf + s * 448 + lane;  // + t*64 per M-tile
#pragma unroll
    for (int t = 0; t < 7; ++t) {
      bf16x8 a = ap[t * 64];
      acc0[t] = __builtin_amdgcn_mfma_f32_16x16x32_bf16(a, b0, acc0[t], 0, 0, 0);
      acc1[t] = __builtin_amdgcn_mfma_f32_16x16x32_bf16(a, b1, acc1[t], 0, 0, 0);
    }
  }

  // C/D layout: col = lane&15, row = (lane>>4)*4 + reg  (per M-tile t: +t*16)
#pragma unroll
  for (int t = 0; t < 7; ++t) {
    const int mbase = t * 16 + q * 4;
#pragma unroll
    for (int r = 0; r < 4; ++r) {
      const int m = mbase + r;
      if (m < NUM_CHUNKS) {
        __builtin_nontemporal_store(acc0[t][r], out + (long)m * N_COLS + col0);
        __builtin_nontemporal_store(acc1[t][r], out + (long)m * N_COLS + col1);
      }
    }
  }
}

extern "C" void kernel_launch(void* const* d_in, const int* in_sizes, int n_in,
                              void* d_out, int out_size, void* d_ws, size_t ws_size,
                              hipStream_t stream) {
  const float* pref      = (const float*)d_in[0];
  const float* pref_emb  = (const float*)d_in[1];
  const float* chunk_emb = (const float*)d_in[2];
  const float* W1 = (const float*)d_in[3];
  const float* b1 = (const float*)d_in[4];
  const float* W2 = (const float*)d_in[5];
  const float* b2 = (const float*)d_in[6];
  const float* W3 = (const float*)d_in[7];
  const float* b3 = (const float*)d_in[8];
  const float* ws = (const float*)d_in[9];
  float* out = (float*)d_out;
  __bf16* repf = (__bf16*)d_ws;

  // zero the fragment buffer so padded chunks m=105..111 contribute 0
  hipMemsetAsync(d_ws, 0, REP_FRAG_BYTES, stream);
  mlp_kernel<<<NUM_CHUNKS, 256, 0, stream>>>(pref, pref_emb, chunk_emb,
                                             W1, b1, W2, b2, W3, b3, repf);
  gemm_ws<<<N_COLS / 32, 64, 0, stream>>>(ws, (const bf16x8*)d_ws, out);
}